// Round 2
// baseline (273.968 us; speedup 1.0000x reference)
//
#include <hip/hip_runtime.h>
#include <hip/hip_cooperative_groups.h>
#include <math.h>

namespace cg = cooperative_groups;

#define BATCH 8
#define NPRED 8192
#define MPART 2048
#define NPTS  (BATCH * NPRED)      // 65536 queries
#define QPL   4                    // queries per lane
#define SPLIT 16                   // 16 waves = 16 M-splits per block
#define PTS_PER_SPLIT (MPART / SPLIT)   // 128
#define GPS   (PTS_PER_SPLIT / 4)       // 32 groups of 4 points per split
#define QPB   256                  // queries per block (4 qpl * 64 lanes)
#define NBLK  (NPTS / QPB)         // 256 blocks (== 256 CUs, 1 block/CU)
#define BASE_ALPHA 0.05f
#define EPS 1e-6f

// LDS: 32 KB grouped-SoA P' tile + 32 KB scratch (raw-partial staging, then
// u64 key buffer) + merged per-query results + wave maxes.  ~66 KB total.
struct SMem {
    float4 tileP[2048];                   // grouped-SoA P' for this batch
    unsigned long long lk[SPLIT * QPB];   // staging scratch / key buffer
    float md_s[QPB];
    int   idx_s[QPB];
    float smax[4];
};

// One NN pass over the resident LDS tile (identical FP ops to the proven
// round-0 kernel: grouped argmin with bit-exact epilogue recompute, u64-key
// cross-split merge, per-block max written to bmax_entry).
__device__ __forceinline__ void nn_pass(
    SMem& sm, int qb, int tid, int wave, int lane, int split,
    const float axq[QPL], const float ayq[QPL], const float azq[QPL],
    const float a2q[QPL], float* __restrict__ bmax_entry)
{
    const float4* wp = sm.tileP + split * (GPS * 4);
    float best[QPL]; int bg[QPL];
    #pragma unroll
    for (int j = 0; j < QPL; ++j) { best[j] = 1e30f; bg[j] = 0; }

    #pragma unroll 2
    for (int i = 0; i < GPS; ++i) {
        const float4 X = wp[4 * i + 0];
        const float4 Y = wp[4 * i + 1];
        const float4 Z = wp[4 * i + 2];
        const float4 W = wp[4 * i + 3];
        #pragma unroll
        for (int j = 0; j < QPL; ++j) {
            const float ax = axq[j], ay = ayq[j], az = azq[j];
            const float d0 = fmaf(Z.x, az, fmaf(Y.x, ay, X.x * ax)) + W.x;
            const float d1 = fmaf(Z.y, az, fmaf(Y.y, ay, X.y * ax)) + W.y;
            const float d2 = fmaf(Z.z, az, fmaf(Y.z, ay, X.z * ax)) + W.z;
            const float d3 = fmaf(Z.w, az, fmaf(Y.w, ay, X.w * ax)) + W.w;
            const float gm = fminf(fminf(fminf(d0, d1), d2), d3);
            if (gm < best[j]) bg[j] = i;       // strict <: earliest group wins
            best[j] = fminf(best[j], gm);
        }
    }

    // Bit-exact epilogue: recover element index within the winning group.
    unsigned long long key[QPL];
    #pragma unroll
    for (int j = 0; j < QPL; ++j) {
        const int gi = bg[j];
        const float4 X = wp[4 * gi + 0];
        const float4 Y = wp[4 * gi + 1];
        const float4 Z = wp[4 * gi + 2];
        const float4 W = wp[4 * gi + 3];
        const float ax = axq[j], ay = ayq[j], az = azq[j];
        const float d0 = fmaf(Z.x, az, fmaf(Y.x, ay, X.x * ax)) + W.x;
        const float d1 = fmaf(Z.y, az, fmaf(Y.y, ay, X.y * ax)) + W.y;
        const float d2 = fmaf(Z.z, az, fmaf(Y.z, ay, X.z * ax)) + W.z;
        const float bv = best[j];
        int c;
        if      (d0 == bv) c = 0;
        else if (d1 == bv) c = 1;
        else if (d2 == bv) c = 2;
        else               c = 3;
        const int m = (split << 7) + (gi << 2) + c;   // index within batch
        const float dd = fmaxf(bv + a2q[j], 0.0f);    // nonneg -> uint-ordered
        key[j] = ((unsigned long long)__float_as_uint(dd) << 32) | (unsigned)m;
    }

    __syncthreads();   // all prior readers of lk / md_s are done
    #pragma unroll
    for (int j = 0; j < QPL; ++j)
        sm.lk[split * QPB + (j << 6) + lane] = key[j];
    __syncthreads();

    // Cross-split merge: u64 min == lexicographic (d^2, first index).
    if (wave < 4) {
        const int q2 = (wave << 6) + lane;   // 0..255
        unsigned long long kk = sm.lk[q2];
        #pragma unroll
        for (int s = 1; s < SPLIT; ++s) {
            const unsigned long long k = sm.lk[s * QPB + q2];
            if (k < kk) kk = k;
        }
        const float md = sqrtf(__uint_as_float((unsigned)(kk >> 32)));
        sm.md_s[q2]  = md;
        sm.idx_s[q2] = (int)(kk & 0xffffffffu);
        float w = md;
        #pragma unroll
        for (int o = 32; o > 0; o >>= 1) w = fmaxf(w, __shfl_down(w, o, 64));
        if (lane == 0) sm.smax[wave] = w;
    }
    __syncthreads();
    if (tid == 0)
        *bmax_entry = fmaxf(fmaxf(sm.smax[0], sm.smax[1]),
                            fmaxf(sm.smax[2], sm.smax[3]));
}

// Single cooperative kernel: prep + nn1 + blend1 + nn2 + blend2.
// Grid = 256 blocks x 1024 threads = 1 block/CU; two grid.sync()s carry the
// only cross-block dependency (per-batch max of min-dist, 32 floats/batch).
__global__ void __launch_bounds__(1024) fused_kernel(
    const float* __restrict__ pred,     // [8,8192,3]
    const float* __restrict__ partial,  // [8,2048,3]
    float* __restrict__ out,            // [8,8192,3]
    float* __restrict__ bmax1,          // [NBLK]
    float* __restrict__ bmax2)          // [NBLK]
{
    __shared__ SMem sm;
    cg::grid_group grid = cg::this_grid();

    const int qb   = blockIdx.x;
    const int b    = qb >> 5;               // 32 blocks per batch
    const int tid  = threadIdx.x;
    const int wave = tid >> 6, lane = tid & 63;
    const int split = wave;

    // ---- queries (iter-1 positions), same ops as round-0 non-FUSE path ----
    float axq[QPL], ayq[QPL], azq[QPL], a2q[QPL];
    #pragma unroll
    for (int j = 0; j < QPL; ++j) {
        const int t = (qb << 8) + (j << 6) + lane;
        const float* p = pred + 3u * (unsigned)t;
        axq[j] = p[0]; ayq[j] = p[1]; azq[j] = p[2];
    }
    #pragma unroll
    for (int j = 0; j < QPL; ++j)
        a2q[j] = fmaf(axq[j], axq[j], fmaf(ayq[j], ayq[j], azq[j] * azq[j]));

    // ---- stage raw partial (24 KB, coalesced float4) into lk scratch ----
    {
        float4* raws = (float4*)sm.lk;
        const float4* psrc = (const float4*)(partial + (size_t)b * MPART * 3);
        raws[tid] = psrc[tid];
        if (tid < 512) raws[tid + 1024] = psrc[tid + 1024];
    }
    __syncthreads();

    // ---- build grouped-SoA P' tile (identical FP ops to prep_kernel) ----
    {
        const float* rf = (const float*)sm.lk;
        float* tpf = (float*)sm.tileP;
        #pragma unroll
        for (int k = 0; k < 2; ++k) {
            const int m = tid + k * 1024;
            const float x = rf[3 * m], y = rf[3 * m + 1], z = rf[3 * m + 2];
            const int g = m >> 2, c = m & 3;
            float* basep = tpf + g * 16 + c;
            basep[0]  = -2.0f * x;
            basep[4]  = -2.0f * y;
            basep[8]  = -2.0f * z;
            basep[12] = fmaf(x, x, fmaf(y, y, z * z));
        }
    }
    __syncthreads();

    // ---- iter 1: NN ----
    nn_pass(sm, qb, tid, wave, lane, split, axq, ayq, azq, a2q, bmax1 + qb);
    __threadfence();
    grid.sync();

    // maxv over the batch's 32 block maxima (identical reduce to round-0).
    float v = bmax1[(b << 5) + (lane & 31)];
    #pragma unroll
    for (int o = 32; o > 0; o >>= 1) v = fmaxf(v, __shfl_down(v, o, 64));
    const float maxv1 = __shfl(v, 0, 64);

    // ---- iter-1 blend, fully in registers; nearest recovered from P' ----
    // -2x stored exactly; -0.5f * (-2x) == x bit-exactly (pow2 scaling).
    const float* tpf = (const float*)sm.tileP;
    #pragma unroll
    for (int j = 0; j < QPL; ++j) {
        const int q = (j << 6) + lane;
        const float md = sm.md_s[q];
        const int  id  = sm.idx_s[q];
        const float alpha = BASE_ALPHA * (2.0f - md / (maxv1 + EPS));
        const int g = id >> 2, c = id & 3;
        const float nbx = -0.5f * tpf[g * 16 + c];
        const float nby = -0.5f * tpf[g * 16 + 4 + c];
        const float nbz = -0.5f * tpf[g * 16 + 8 + c];
        const float px = axq[j], py = ayq[j], pz = azq[j];
        axq[j] = fmaf(alpha, nbx - px, px);
        ayq[j] = fmaf(alpha, nby - py, py);
        azq[j] = fmaf(alpha, nbz - pz, pz);
    }
    #pragma unroll
    for (int j = 0; j < QPL; ++j)
        a2q[j] = fmaf(axq[j], axq[j], fmaf(ayq[j], ayq[j], azq[j] * azq[j]));

    // ---- iter 2: NN on refined-1 (tile still resident) ----
    nn_pass(sm, qb, tid, wave, lane, split, axq, ayq, azq, a2q, bmax2 + qb);
    __threadfence();
    grid.sync();

    float v2 = bmax2[(b << 5) + (lane & 31)];
    #pragma unroll
    for (int o = 32; o > 0; o >>= 1) v2 = fmaxf(v2, __shfl_down(v2, o, 64));
    const float maxv2 = __shfl(v2, 0, 64);

    // ---- final blend + store. Each wave holds ALL 256 block queries
    // (q = (j<<6)+lane); waves 0..3 write slice j == wave exactly once. ----
    if (wave < 4) {
        const int j = wave;
        const int q = (j << 6) + lane;
        const float md = sm.md_s[q];
        const int  id  = sm.idx_s[q];
        const float alpha = BASE_ALPHA * (2.0f - md / (maxv2 + EPS));
        const int g = id >> 2, c = id & 3;
        const float nbx = -0.5f * tpf[g * 16 + c];
        const float nby = -0.5f * tpf[g * 16 + 4 + c];
        const float nbz = -0.5f * tpf[g * 16 + 8 + c];
        const float px = axq[j], py = ayq[j], pz = azq[j];
        const int t = (qb << 8) + q;
        float* o = out + 3u * (unsigned)t;
        o[0] = fmaf(alpha, nbx - px, px);
        o[1] = fmaf(alpha, nby - py, py);
        o[2] = fmaf(alpha, nbz - pz, pz);
    }
}

extern "C" void kernel_launch(void* const* d_in, const int* in_sizes, int n_in,
                              void* d_out, int out_size, void* d_ws, size_t ws_size,
                              hipStream_t stream) {
    const float* pred    = (const float*)d_in[0];   // [8,8192,3] fp32
    const float* partial = (const float*)d_in[1];   // [8,2048,3] fp32
    float* out = (float*)d_out;

    char* ws = (char*)d_ws;
    float* bmax1 = (float*)ws;            // 1 KB
    float* bmax2 = bmax1 + NBLK;          // 1 KB

    void* args[] = {(void*)&pred, (void*)&partial, (void*)&out,
                    (void*)&bmax1, (void*)&bmax2};
    hipLaunchCooperativeKernel((const void*)fused_kernel,
                               dim3(NBLK), dim3(1024), args, 0, stream);
}

// Round 3
// 115.386 us; speedup vs baseline: 2.3744x; 2.3744x over previous
//
#include <hip/hip_runtime.h>
#include <math.h>

#define BATCH 8
#define NPRED 8192
#define MPART 2048
#define NPTS  (BATCH * NPRED)      // 65536 queries
#define MTOT  (BATCH * MPART)      // 16384 partial points
#define QPL   4                    // queries per lane
#define SPLIT 16                   // 16 waves = 16 M-splits per block
#define PTS_PER_SPLIT (MPART / SPLIT)   // 128
#define GPS   (PTS_PER_SPLIT / 4)       // 32 groups of 4 points per split
#define QPB   256                  // queries per block (4 qpl * 64 lanes)
#define NBLK  (NPTS / QPB)         // 256 blocks
#define BASE_ALPHA 0.05f
#define EPS 1e-6f

// Grouped-SoA P': for each group g of 4 points, 4 consecutive float4s:
//   ppg[4g+0]={-2x0..-2x3} ppg[4g+1]={-2y..} ppg[4g+2]={-2z..} ppg[4g+3]={|b|^2..}
// near4[m] = (x,y,z,0) for the single-float4 nearest gather in updates.
__global__ __launch_bounds__(256) void prep_kernel(const float* __restrict__ partial,
                                                   float* __restrict__ ppgf,
                                                   float4* __restrict__ near4) {
    const int m = blockIdx.x * 256 + threadIdx.x;   // 64 blocks cover MTOT
    const float* p = partial + 3u * (unsigned)m;
    const float x = p[0], y = p[1], z = p[2];
    const int g = m >> 2, c = m & 3;
    float* base = ppgf + (size_t)g * 16 + c;
    base[0]  = -2.0f * x;
    base[4]  = -2.0f * y;
    base[8]  = -2.0f * z;
    base[12] = fmaf(x, x, fmaf(y, y, z * z));
    near4[m] = make_float4(x, y, z, 0.0f);
}

// Read a wave-uniform float from lane l (compile-time constant after unroll).
__device__ __forceinline__ float rlf(float v, int l) {
    return __int_as_float(__builtin_amdgcn_readlane(__float_as_int(v), l));
}

// Block = 1024 threads = 16 waves. Wave w scans M-split w (128 pts) for the
// block's 256 queries (4 per lane). The point tile lives in REGISTERS:
// lane l holds ppg float4 #l (t0) and #(64+l) (t1) of its split, loaded
// coalesced from global once. Group g's 16 wave-uniform values are extracted
// via v_readlane (VALU pipe, per-SIMD) — zero LDS traffic in the scan, which
// was the LDS-broadcast bottleneck (7.36M conflict cycles measured in r2).
// LDS holds only the 32 KB cross-split u64 key buffer.
// Grouped argmin: loop tracks (group-min, group-id); epilogue re-gathers the
// winning group from L2-resident ppg (identical bytes) and recomputes the 4
// dots with IDENTICAL fp ops (bit-exact) to recover the element index;
// strict '<' + lowest-c tie-break = first-occurrence.
// FUSE: apply previous iteration's blend in the prologue (round-0 pattern).
template <bool FUSE>
__global__ __launch_bounds__(1024) void nn_kernel(
    const float* __restrict__ src,      // [B,N,3] base positions
    const float4* __restrict__ ppg,     // [MTOT] grouped-SoA P'
    const float4* __restrict__ near4,   // [MTOT] raw partial
    const float* md_in, const int* idx_in,   // FUSE only (may alias outputs)
    const float* __restrict__ bmax_in,  // [NBLK] per-block max from prev pass
    float* __restrict__ refined_out,    // [B,N,3] (FUSE)
    float* md_out, int* idx_out,        // [B*N]
    float* __restrict__ bmax_out)       // [NBLK]
{
    __shared__ unsigned long long lk[SPLIT * QPB];   // 32 KB key buffer
    __shared__ float smax[4];

    const int qb   = blockIdx.x;
    const int b    = qb >> 5;               // 32 blocks per batch
    const int tid  = threadIdx.x;
    const int wave = tid >> 6, lane = tid & 63;
    const int split = wave;

    // Register tile: this wave's 128 float4 of grouped-SoA P'.
    const float4* wpg = ppg + ((size_t)b << 11) + ((size_t)split << 7);
    const float4 t0 = wpg[lane];
    const float4 t1 = wpg[64 + lane];

    // Load / compute the 4 per-lane query positions.
    float axq[QPL], ayq[QPL], azq[QPL], a2q[QPL];
    if (FUSE) {
        float v = bmax_in[(b << 5) + (lane & 31)];
        #pragma unroll
        for (int o = 32; o > 0; o >>= 1) v = fmaxf(v, __shfl_down(v, o, 64));
        const float maxv = __shfl(v, 0, 64);
        #pragma unroll
        for (int j = 0; j < QPL; ++j) {
            const int t = (qb << 8) + (j << 6) + lane;
            const float md = md_in[t];
            const int   id = idx_in[t];
            const float alpha = BASE_ALPHA * (2.0f - md / (maxv + EPS));
            const float4 nb = near4[((size_t)b << 11) + id];
            const float* p = src + 3u * (unsigned)t;
            const float px = p[0], py = p[1], pz = p[2];
            axq[j] = fmaf(alpha, nb.x - px, px);
            ayq[j] = fmaf(alpha, nb.y - py, py);
            azq[j] = fmaf(alpha, nb.z - pz, pz);
            if (split == 0) {               // one copy of refined-1 to ws
                float* o = refined_out + 3u * (unsigned)t;
                o[0] = axq[j]; o[1] = ayq[j]; o[2] = azq[j];
            }
        }
    } else {
        #pragma unroll
        for (int j = 0; j < QPL; ++j) {
            const int t = (qb << 8) + (j << 6) + lane;
            const float* p = src + 3u * (unsigned)t;
            axq[j] = p[0]; ayq[j] = p[1]; azq[j] = p[2];
        }
    }
    #pragma unroll
    for (int j = 0; j < QPL; ++j)
        a2q[j] = fmaf(axq[j], axq[j], fmaf(ayq[j], ayq[j], azq[j] * azq[j]));

    float best[QPL]; int bg[QPL];
    #pragma unroll
    for (int j = 0; j < QPL; ++j) { best[j] = 1e30f; bg[j] = 0; }

    // Scan: 32 groups, fully unrolled so readlane indices are constants.
    // Group i (i<16) = lanes 4i..4i+3 of t0; (i>=16) = lanes 4(i-16).. of t1.
    #pragma unroll
    for (int i = 0; i < GPS; ++i) {
        const float4 t = (i < 16) ? t0 : t1;
        const int l0 = (i & 15) << 2;
        const float Xx = rlf(t.x, l0 + 0), Xy = rlf(t.y, l0 + 0),
                    Xz = rlf(t.z, l0 + 0), Xw = rlf(t.w, l0 + 0);
        const float Yx = rlf(t.x, l0 + 1), Yy = rlf(t.y, l0 + 1),
                    Yz = rlf(t.z, l0 + 1), Yw = rlf(t.w, l0 + 1);
        const float Zx = rlf(t.x, l0 + 2), Zy = rlf(t.y, l0 + 2),
                    Zz = rlf(t.z, l0 + 2), Zw = rlf(t.w, l0 + 2);
        const float Wx = rlf(t.x, l0 + 3), Wy = rlf(t.y, l0 + 3),
                    Wz = rlf(t.z, l0 + 3), Ww = rlf(t.w, l0 + 3);
        #pragma unroll
        for (int j = 0; j < QPL; ++j) {
            const float ax = axq[j], ay = ayq[j], az = azq[j];
            const float d0 = fmaf(Zx, az, fmaf(Yx, ay, Xx * ax)) + Wx;
            const float d1 = fmaf(Zy, az, fmaf(Yy, ay, Xy * ax)) + Wy;
            const float d2 = fmaf(Zz, az, fmaf(Yz, ay, Xz * ax)) + Wz;
            const float d3 = fmaf(Zw, az, fmaf(Yw, ay, Xw * ax)) + Ww;
            const float gm = fminf(fminf(fminf(d0, d1), d2), d3);
            if (gm < best[j]) bg[j] = i;       // strict <: earliest group wins
            best[j] = fminf(best[j], gm);
        }
    }

    // Epilogue: recover element index within the winning group (bit-exact
    // recompute from the same bytes in L2-resident ppg; fminf returns one
    // operand exactly, so an equality must hit).
    unsigned long long key[QPL];
    #pragma unroll
    for (int j = 0; j < QPL; ++j) {
        const int gi = bg[j];
        const float4 X = wpg[4 * gi + 0];
        const float4 Y = wpg[4 * gi + 1];
        const float4 Z = wpg[4 * gi + 2];
        const float4 W = wpg[4 * gi + 3];
        const float ax = axq[j], ay = ayq[j], az = azq[j];
        const float d0 = fmaf(Z.x, az, fmaf(Y.x, ay, X.x * ax)) + W.x;
        const float d1 = fmaf(Z.y, az, fmaf(Y.y, ay, X.y * ax)) + W.y;
        const float d2 = fmaf(Z.z, az, fmaf(Y.z, ay, X.z * ax)) + W.z;
        const float bv = best[j];
        int c;
        if      (d0 == bv) c = 0;
        else if (d1 == bv) c = 1;
        else if (d2 == bv) c = 2;
        else               c = 3;
        const int m = (split << 7) + (gi << 2) + c;   // index within batch
        const float dd = fmaxf(bv + a2q[j], 0.0f);    // nonneg -> uint-ordered
        key[j] = ((unsigned long long)__float_as_uint(dd) << 32) | (unsigned)m;
    }

    #pragma unroll
    for (int j = 0; j < QPL; ++j)
        lk[split * QPB + (j << 6) + lane] = key[j];
    __syncthreads();

    // Cross-split merge: u64 min == lexicographic (d^2, first index).
    if (wave < 4) {
        const int q2 = (wave << 6) + lane;   // 0..255
        unsigned long long kk = lk[q2];
        #pragma unroll
        for (int s = 1; s < SPLIT; ++s) {
            const unsigned long long k = lk[s * QPB + q2];
            if (k < kk) kk = k;
        }
        const float md = sqrtf(__uint_as_float((unsigned)(kk >> 32)));
        const int t2 = (qb << 8) + q2;
        md_out[t2]  = md;
        idx_out[t2] = (int)(kk & 0xffffffffu);
        float w = md;
        #pragma unroll
        for (int o = 32; o > 0; o >>= 1) w = fmaxf(w, __shfl_down(w, o, 64));
        if (lane == 0) smax[wave] = w;
    }
    __syncthreads();
    if (tid == 0)
        bmax_out[qb] = fmaxf(fmaxf(smax[0], smax[1]), fmaxf(smax[2], smax[3]));
}

// Final blend: out = refined1 + alpha2*(nearest2 - refined1).
__global__ __launch_bounds__(256) void update_kernel(
    const float* __restrict__ refined1,
    const float4* __restrict__ near4,
    const float* __restrict__ md2,
    const int*   __restrict__ idx2,
    const float* __restrict__ bmax2,   // [NBLK]
    float* __restrict__ out)
{
    const int t = blockIdx.x * 256 + threadIdx.x;
    const int b = t >> 13;
    const int lane = threadIdx.x & 63;
    float v = bmax2[(b << 5) + (lane & 31)];
    #pragma unroll
    for (int o = 32; o > 0; o >>= 1) v = fmaxf(v, __shfl_down(v, o, 64));
    const float maxv = __shfl(v, 0, 64);
    const float md = md2[t];
    const int   id = idx2[t];
    const float alpha = BASE_ALPHA * (2.0f - md / (maxv + EPS));
    const float4 nb = near4[((size_t)b << 11) + id];
    const float* p = refined1 + 3u * (unsigned)t;
    const float px = p[0], py = p[1], pz = p[2];
    float* o = out + 3u * (unsigned)t;
    o[0] = fmaf(alpha, nb.x - px, px);
    o[1] = fmaf(alpha, nb.y - py, py);
    o[2] = fmaf(alpha, nb.z - pz, pz);
}

extern "C" void kernel_launch(void* const* d_in, const int* in_sizes, int n_in,
                              void* d_out, int out_size, void* d_ws, size_t ws_size,
                              hipStream_t stream) {
    const float* pred    = (const float*)d_in[0];   // [8,8192,3] fp32
    const float* partial = (const float*)d_in[1];   // [8,2048,3] fp32
    float* out = (float*)d_out;

    char* ws = (char*)d_ws;                          // 16B-aligned chunks first
    float4* ppg   = (float4*)ws;                     // 256 KB grouped-SoA P'
    float4* near4 = (float4*)(ws + 262144);          // 256 KB
    float*  ref1  = (float*)(ws + 524288);           // 768 KB
    float*  md1   = (float*)(ws + 1310720);          // 256 KB
    int*    idx1  = (int*)(ws + 1572864);            // 256 KB
    float*  bmax1 = (float*)(ws + 1835008);          // 1 KB
    float*  bmax2 = bmax1 + NBLK;                    // 1 KB

    prep_kernel<<<MTOT / 256, 256, 0, stream>>>(partial, (float*)ppg, near4);

    // Iter 1 NN: pred -> md1/idx1/bmax1
    nn_kernel<false><<<NBLK, 1024, 0, stream>>>(
        pred, ppg, near4, nullptr, nullptr, nullptr, nullptr, md1, idx1, bmax1);

    // Iter 1 update fused into iter 2 NN: writes ref1, overwrites md1/idx1.
    nn_kernel<true><<<NBLK, 1024, 0, stream>>>(
        pred, ppg, near4, md1, idx1, bmax1, ref1, md1, idx1, bmax2);

    // Iter 2 update: ref1 -> out
    update_kernel<<<NPTS / 256, 256, 0, stream>>>(ref1, near4, md1, idx1, bmax2, out);
}

// Round 4
// 95.858 us; speedup vs baseline: 2.8581x; 1.2037x over previous
//
#include <hip/hip_runtime.h>
#include <math.h>

#define BATCH 8
#define NPRED 8192
#define MPART 2048
#define NPTS  (BATCH * NPRED)      // 65536 queries
#define QPL   4                    // queries per lane
#define SPLIT 16                   // 16 waves = 16 M-splits per block
#define PTS_PER_SPLIT (MPART / SPLIT)   // 128
#define GPS   (PTS_PER_SPLIT / 4)       // 32 groups of 4 points per split
#define QPB   256                  // queries per block (4 qpl * 64 lanes)
#define NBLK  (NPTS / QPB)         // 256 blocks (1 per CU)
#define BASE_ALPHA 0.05f
#define EPS 1e-6f

__device__ __forceinline__ unsigned long long shflx_u64(unsigned long long v, int m) {
    unsigned lo = (unsigned)v, hi = (unsigned)(v >> 32);
    lo = (unsigned)__shfl_xor((int)lo, m, 64);
    hi = (unsigned)__shfl_xor((int)hi, m, 64);
    return ((unsigned long long)hi << 32) | lo;
}

// Block = 1024 threads = 16 waves. Wave w scans M-split w (128 pts) for the
// block's 256 queries (4 per lane). Each block builds its batch's grouped-SoA
// P' tile in LDS from raw partial (bit-identical ops to the old prep_kernel;
// proven absmax 0.0 in round 2) — prep_kernel and its launch gap are gone.
// Scan: 2-deep register prefetch over broadcast ds_read_b128 (the proven
// round-0 mechanism; readlane/s_load variants measured slower in r1/r3).
// Grouped argmin: loop tracks (group-min, group-id); epilogue recomputes the
// winning group's 4 dots with IDENTICAL fp ops (bit-exact) to recover the
// element index; strict '<' + lowest-c tie-break = first-occurrence.
// Keys land in the (dead) staging scratch -> one barrier fewer than round 0.
// Merge: all 16 waves (4 u64 LDS reads/lane + 2 u64 shuffles); u64-min is
// commutative so the result is bit-identical to the serial merge.
// FUSE: apply previous iteration's blend in the prologue; nearest gathered
// from the LDS tile via exact -0.5f*(-2x) reconstruction.
template <bool FUSE>
__global__ __launch_bounds__(1024) void nn_kernel(
    const float* __restrict__ src,      // [B,N,3] base positions
    const float* __restrict__ partial,  // [B,M,3] raw partial
    const float* md_in, const int* idx_in,   // FUSE only (alias outputs)
    const float* __restrict__ bmax_in,  // [NBLK] per-block max from prev pass
    float* __restrict__ refined_out,    // [B,N,3] (FUSE)
    float* md_out, int* idx_out,        // [B*N]
    float* __restrict__ bmax_out)       // [NBLK]
{
    __shared__ float4 tileP[2048];                 // 32 KB grouped-SoA P'
    __shared__ unsigned long long lk[SPLIT * QPB]; // 32 KB scratch -> keys
    __shared__ float smax[SPLIT];

    const int qb   = blockIdx.x;
    const int b    = qb >> 5;               // 32 blocks per batch
    const int tid  = threadIdx.x;
    const int wave = tid >> 6, lane = tid & 63;
    const int split = wave;

    // ---- stage raw partial (24 KB, coalesced float4) into lk scratch ----
    {
        float4* raws = (float4*)lk;
        const float4* psrc = (const float4*)(partial + (size_t)b * MPART * 3);
        raws[tid] = psrc[tid];
        if (tid < 512) raws[tid + 1024] = psrc[tid + 1024];
    }

    // ---- query prologue, part 1 (no tile dependency; overlaps staging) ----
    float axq[QPL], ayq[QPL], azq[QPL], a2q[QPL];
    float alpha_[QPL]; int id_[QPL];
    if (FUSE) {
        float v = bmax_in[(b << 5) + (lane & 31)];
        #pragma unroll
        for (int o = 32; o > 0; o >>= 1) v = fmaxf(v, __shfl_down(v, o, 64));
        const float maxv = __shfl(v, 0, 64);
        #pragma unroll
        for (int j = 0; j < QPL; ++j) {
            const int t = (qb << 8) + (j << 6) + lane;
            const float md = md_in[t];
            id_[j]    = idx_in[t];
            alpha_[j] = BASE_ALPHA * (2.0f - md / (maxv + EPS));
            const float* p = src + 3u * (unsigned)t;
            axq[j] = p[0]; ayq[j] = p[1]; azq[j] = p[2];
        }
    } else {
        #pragma unroll
        for (int j = 0; j < QPL; ++j) {
            const int t = (qb << 8) + (j << 6) + lane;
            const float* p = src + 3u * (unsigned)t;
            axq[j] = p[0]; ayq[j] = p[1]; azq[j] = p[2];
        }
    }

    __syncthreads();   // staging complete

    // ---- build grouped-SoA P' tile (identical FP ops to old prep_kernel) --
    {
        const float* rf = (const float*)lk;
        float* tpf = (float*)tileP;
        #pragma unroll
        for (int k = 0; k < 2; ++k) {
            const int m = tid + (k << 10);
            const float x = rf[3 * m], y = rf[3 * m + 1], z = rf[3 * m + 2];
            const int g = m >> 2, c = m & 3;
            float* basep = tpf + g * 16 + c;
            basep[0]  = -2.0f * x;
            basep[4]  = -2.0f * y;
            basep[8]  = -2.0f * z;
            basep[12] = fmaf(x, x, fmaf(y, y, z * z));
        }
    }
    __syncthreads();   // tile ready; raw scratch in lk is now dead

    // ---- FUSE blend (nearest from tile: -0.5f*(-2x) == x bit-exactly) ----
    const float* tpf = (const float*)tileP;
    if (FUSE) {
        #pragma unroll
        for (int j = 0; j < QPL; ++j) {
            const int g = id_[j] >> 2, c = id_[j] & 3;
            const float nbx = -0.5f * tpf[g * 16 + c];
            const float nby = -0.5f * tpf[g * 16 + 4 + c];
            const float nbz = -0.5f * tpf[g * 16 + 8 + c];
            const float px = axq[j], py = ayq[j], pz = azq[j];
            axq[j] = fmaf(alpha_[j], nbx - px, px);
            ayq[j] = fmaf(alpha_[j], nby - py, py);
            azq[j] = fmaf(alpha_[j], nbz - pz, pz);
            if (split == 0) {               // one copy of refined-1 to ws
                const int t = (qb << 8) + (j << 6) + lane;
                float* o = refined_out + 3u * (unsigned)t;
                o[0] = axq[j]; o[1] = ayq[j]; o[2] = azq[j];
            }
        }
    }
    #pragma unroll
    for (int j = 0; j < QPL; ++j)
        a2q[j] = fmaf(axq[j], axq[j], fmaf(ayq[j], ayq[j], azq[j] * azq[j]));

    // ---- scan: 2-deep register prefetch over broadcast b128 reads ----
    const float4* wp = tileP + split * (GPS * 4);
    float best[QPL]; int bg[QPL];
    #pragma unroll
    for (int j = 0; j < QPL; ++j) { best[j] = 1e30f; bg[j] = 0; }

    auto step = [&](int i, const float4& X, const float4& Y,
                    const float4& Z, const float4& W) {
        #pragma unroll
        for (int j = 0; j < QPL; ++j) {
            const float ax = axq[j], ay = ayq[j], az = azq[j];
            const float d0 = fmaf(Z.x, az, fmaf(Y.x, ay, X.x * ax)) + W.x;
            const float d1 = fmaf(Z.y, az, fmaf(Y.y, ay, X.y * ax)) + W.y;
            const float d2 = fmaf(Z.z, az, fmaf(Y.z, ay, X.z * ax)) + W.z;
            const float d3 = fmaf(Z.w, az, fmaf(Y.w, ay, X.w * ax)) + W.w;
            const float gm = fminf(fminf(fminf(d0, d1), d2), d3);
            if (gm < best[j]) bg[j] = i;       // strict <: earliest group wins
            best[j] = fminf(best[j], gm);
        }
    };

    float4 Xc = wp[0], Yc = wp[1], Zc = wp[2], Wc = wp[3];
    #pragma unroll 4
    for (int i = 0; i < GPS - 1; ++i) {
        const float4 Xn = wp[4 * i + 4];
        const float4 Yn = wp[4 * i + 5];
        const float4 Zn = wp[4 * i + 6];
        const float4 Wn = wp[4 * i + 7];
        step(i, Xc, Yc, Zc, Wc);
        Xc = Xn; Yc = Yn; Zc = Zn; Wc = Wn;
    }
    step(GPS - 1, Xc, Yc, Zc, Wc);

    // ---- epilogue: bit-exact recompute of winning group -> element index --
    unsigned long long key[QPL];
    #pragma unroll
    for (int j = 0; j < QPL; ++j) {
        const int gi = bg[j];
        const float4 X = wp[4 * gi + 0];
        const float4 Y = wp[4 * gi + 1];
        const float4 Z = wp[4 * gi + 2];
        const float4 W = wp[4 * gi + 3];
        const float ax = axq[j], ay = ayq[j], az = azq[j];
        const float d0 = fmaf(Z.x, az, fmaf(Y.x, ay, X.x * ax)) + W.x;
        const float d1 = fmaf(Z.y, az, fmaf(Y.y, ay, X.y * ax)) + W.y;
        const float d2 = fmaf(Z.z, az, fmaf(Y.z, ay, X.z * ax)) + W.z;
        const float bv = best[j];
        int c;
        if      (d0 == bv) c = 0;
        else if (d1 == bv) c = 1;
        else if (d2 == bv) c = 2;
        else               c = 3;
        const int m = (split << 7) + (gi << 2) + c;   // index within batch
        const float dd = fmaxf(bv + a2q[j], 0.0f);    // nonneg -> uint-ordered
        key[j] = ((unsigned long long)__float_as_uint(dd) << 32) | (unsigned)m;
    }

    // Keys go to lk (scratch is dead): no pre-write barrier needed.
    #pragma unroll
    for (int j = 0; j < QPL; ++j)
        lk[split * QPB + (j << 6) + lane] = key[j];
    __syncthreads();

    // ---- merge across splits, all 16 waves; u64 min == lexicographic ----
    {
        const int q  = (wave << 4) + (lane & 15);   // this lane's query
        const int s0 = (lane >> 4) << 2;            // its 4-split slice
        unsigned long long kk = lk[s0 * QPB + q];
        #pragma unroll
        for (int s = 1; s < 4; ++s) {
            const unsigned long long k = lk[(s0 + s) * QPB + q];
            if (k < kk) kk = k;
        }
        unsigned long long o = shflx_u64(kk, 16);
        if (o < kk) kk = o;
        o = shflx_u64(kk, 32);
        if (o < kk) kk = o;
        const float md = sqrtf(__uint_as_float((unsigned)(kk >> 32)));
        if (lane < 16) {
            const int t2 = (qb << 8) + q;
            md_out[t2]  = md;
            idx_out[t2] = (int)(kk & 0xffffffffu);
        }
        float w = md;
        #pragma unroll
        for (int o2 = 8; o2 > 0; o2 >>= 1) w = fmaxf(w, __shfl_xor(w, o2, 64));
        if (lane == 0) smax[wave] = w;
    }
    __syncthreads();
    if (tid == 0) {
        float m0 = smax[0];
        #pragma unroll
        for (int s = 1; s < SPLIT; ++s) m0 = fmaxf(m0, smax[s]);
        bmax_out[qb] = m0;
    }
}

// Final blend: out = refined1 + alpha2*(nearest2 - refined1).
// Nearest gathered straight from raw partial (same bytes near4 held).
__global__ __launch_bounds__(256) void update_kernel(
    const float* __restrict__ refined1,
    const float* __restrict__ partial,
    const float* __restrict__ md2,
    const int*   __restrict__ idx2,
    const float* __restrict__ bmax2,   // [NBLK]
    float* __restrict__ out)
{
    const int t = blockIdx.x * 256 + threadIdx.x;
    const int b = t >> 13;
    const int lane = threadIdx.x & 63;
    float v = bmax2[(b << 5) + (lane & 31)];
    #pragma unroll
    for (int o = 32; o > 0; o >>= 1) v = fmaxf(v, __shfl_down(v, o, 64));
    const float maxv = __shfl(v, 0, 64);
    const float md = md2[t];
    const int   id = idx2[t];
    const float alpha = BASE_ALPHA * (2.0f - md / (maxv + EPS));
    const float* nbp = partial + 3u * (unsigned)((b << 11) + id);
    const float nbx = nbp[0], nby = nbp[1], nbz = nbp[2];
    const float* p = refined1 + 3u * (unsigned)t;
    const float px = p[0], py = p[1], pz = p[2];
    float* o = out + 3u * (unsigned)t;
    o[0] = fmaf(alpha, nbx - px, px);
    o[1] = fmaf(alpha, nby - py, py);
    o[2] = fmaf(alpha, nbz - pz, pz);
}

extern "C" void kernel_launch(void* const* d_in, const int* in_sizes, int n_in,
                              void* d_out, int out_size, void* d_ws, size_t ws_size,
                              hipStream_t stream) {
    const float* pred    = (const float*)d_in[0];   // [8,8192,3] fp32
    const float* partial = (const float*)d_in[1];   // [8,2048,3] fp32
    float* out = (float*)d_out;

    char* ws = (char*)d_ws;
    float* ref1  = (float*)ws;                 // 768 KB
    float* md1   = (float*)(ws + 786432);      // 256 KB
    int*   idx1  = (int*)(ws + 1048576);       // 256 KB
    float* bmax1 = (float*)(ws + 1310720);     // 1 KB
    float* bmax2 = bmax1 + NBLK;               // 1 KB

    // Iter 1 NN: pred -> md1/idx1/bmax1 (tile built in-block)
    nn_kernel<false><<<NBLK, 1024, 0, stream>>>(
        pred, partial, nullptr, nullptr, nullptr, nullptr, md1, idx1, bmax1);

    // Iter 1 update fused into iter 2 NN: writes ref1, overwrites md1/idx1.
    nn_kernel<true><<<NBLK, 1024, 0, stream>>>(
        pred, partial, md1, idx1, bmax1, ref1, md1, idx1, bmax2);

    // Iter 2 update: ref1 -> out
    update_kernel<<<NPTS / 256, 256, 0, stream>>>(ref1, partial, md1, idx1, bmax2, out);
}